// Round 1
// baseline (114.444 us; speedup 1.0000x reference)
//
#include <hip/hip_runtime.h>
#include <hip/hip_bf16.h>

#define B_DIM 4096
#define V_DIM 2
#define D_DIM 128
#define N_TOT 8192
#define TEMP_INV (1.0f / 0.07f)

typedef float f32x4 __attribute__((ext_vector_type(4)));
typedef __bf16 bf16x8 __attribute__((ext_vector_type(8)));

__device__ __forceinline__ float waveReduceSum(float v) {
#pragma unroll
    for (int off = 32; off > 0; off >>= 1) v += __shfl_xor(v, off);
    return v;
}

// Kernel 1: normalize rows into view-major order (i = v*B + b); emit fp32 + bf16.
// Also zeroes Z and the output accumulator (ws/out are poisoned 0xAA each launch).
__global__ void normalize_kernel(const float* __restrict__ feat,
                                 float* __restrict__ znf,
                                 ushort* __restrict__ znb,
                                 float* __restrict__ Z,
                                 float* __restrict__ lossOut) {
    int gid = blockIdx.x * 256 + threadIdx.x;
    if (gid < N_TOT) Z[gid] = 0.f;
    if (gid == 0) lossOut[0] = 0.f;

    int row = blockIdx.x * 4 + (threadIdx.x >> 6);   // 2048 blocks * 4 waves = 8192 rows
    int lane = threadIdx.x & 63;
    int b = row & (B_DIM - 1);
    int v = row >> 12;                                // B = 4096 = 2^12
    const float* src = feat + ((size_t)b * V_DIM + v) * D_DIM;
    float2 x = *(const float2*)(src + lane * 2);
    float ss = waveReduceSum(x.x * x.x + x.y * x.y);
    float inv = 1.0f / fmaxf(sqrtf(ss), 1e-8f);       // torch CosineSimilarity eps clamp
    float z0 = x.x * inv, z1 = x.y * inv;
    *(float2*)(znf + (size_t)row * D_DIM + lane * 2) = make_float2(z0, z1);
    __hip_bfloat16 h0 = __float2bfloat16(z0);
    __hip_bfloat16 h1 = __float2bfloat16(z1);
    ushort2 u;
    u.x = *reinterpret_cast<ushort*>(&h0);
    u.y = *reinterpret_cast<ushort*>(&h1);
    *(ushort2*)(znb + (size_t)row * D_DIM + lane * 2) = u;
}

// Kernel 2: 128x128 tile of S = zn.znT / T; fused exp + diagonal mask + row-sum.
// K=128 staged fully in LDS once (64 KiB). XOR-swizzle (row&7)<<4 on both the
// LDS write and read side -> conflict-free ds_read_b128 fragment loads.
__global__ __launch_bounds__(256) void sim_kernel(const ushort* __restrict__ znb,
                                                  float* __restrict__ Z) {
    __shared__ __align__(16) ushort As[128 * 128];
    __shared__ __align__(16) ushort Bs[128 * 128];

    const int i0 = blockIdx.x * 128;
    const int j0 = blockIdx.y * 128;
    const int tid = threadIdx.x;

    // Stage both tiles: 2048 16B-chunks each, 8 per thread, coalesced reads.
#pragma unroll
    for (int it = 0; it < 8; ++it) {
        int c = it * 256 + tid;
        int row = c >> 4;
        int chunk = c & 15;
        int swz = (chunk * 16) ^ ((row & 7) << 4);
        uint4 va = *(const uint4*)(znb + (size_t)(i0 + row) * D_DIM + chunk * 8);
        *(uint4*)((char*)As + row * 256 + swz) = va;
        uint4 vb = *(const uint4*)(znb + (size_t)(j0 + row) * D_DIM + chunk * 8);
        *(uint4*)((char*)Bs + row * 256 + swz) = vb;
    }
    __syncthreads();

    const int lane = tid & 63;
    const int wid = tid >> 6;
    const int wr = wid >> 1, wc = wid & 1;   // 2x2 wave grid, 64x64 per wave
    const int l16 = lane & 15;
    const int grp = lane >> 4;

    f32x4 acc[4][4] = {};
#pragma unroll
    for (int kk = 0; kk < 4; ++kk) {
        bf16x8 af[4], bf[4];
        const int kb = kk * 64 + grp * 16;   // byte offset of this lane-group's 8 k-elems
#pragma unroll
        for (int m = 0; m < 4; ++m) {
            int r = wr * 64 + m * 16 + l16;  // A row = lane&15
            af[m] = *(const bf16x8*)((const char*)As + r * 256 + (kb ^ ((r & 7) << 4)));
        }
#pragma unroll
        for (int n = 0; n < 4; ++n) {
            int r = wc * 64 + n * 16 + l16;  // B col = lane&15 (B^T row)
            bf[n] = *(const bf16x8*)((const char*)Bs + r * 256 + (kb ^ ((r & 7) << 4)));
        }
#pragma unroll
        for (int m = 0; m < 4; ++m)
#pragma unroll
            for (int n = 0; n < 4; ++n)
                acc[m][n] = __builtin_amdgcn_mfma_f32_16x16x32_bf16(af[m], bf[n], acc[m][n], 0, 0, 0);
    }

    // Epilogue: scale, exp, mask diagonal, accumulate per-row sums.
    // C/D layout (verified m89): col = lane&15, row = (lane>>4)*4 + reg.
    float esum[4][4];
#pragma unroll
    for (int m = 0; m < 4; ++m)
#pragma unroll
        for (int r = 0; r < 4; ++r) esum[m][r] = 0.f;

#pragma unroll
    for (int m = 0; m < 4; ++m) {
#pragma unroll
        for (int n = 0; n < 4; ++n) {
            int gj = j0 + wc * 64 + n * 16 + l16;
#pragma unroll
            for (int r = 0; r < 4; ++r) {
                int gi = i0 + wr * 64 + m * 16 + grp * 4 + r;
                float e = __expf(acc[m][n][r] * TEMP_INV);
                if (gi != gj) esum[m][r] += e;   // exact diagonal mask
            }
        }
    }

    __syncthreads();                      // all LDS reads done; reuse As as rowsum[2][128]
    float* rowsum = (float*)As;
#pragma unroll
    for (int m = 0; m < 4; ++m) {
#pragma unroll
        for (int r = 0; r < 4; ++r) {
            float vsum = esum[m][r];
            vsum += __shfl_xor(vsum, 1);
            vsum += __shfl_xor(vsum, 2);
            vsum += __shfl_xor(vsum, 4);
            vsum += __shfl_xor(vsum, 8);  // sum over 16 cols within lane-group
            if (l16 == 0) rowsum[wc * 128 + wr * 64 + m * 16 + grp * 4 + r] = vsum;
        }
    }
    __syncthreads();
    if (tid < 128) atomicAdd(&Z[i0 + tid], rowsum[tid] + rowsum[128 + tid]);
}

// Kernel 3: loss = mean_i( log(Z_i) - dot(zn_i, zn_pos(i))/T ), pos(i) = (i+B) mod N.
__global__ void reduce_kernel(const float* __restrict__ znf,
                              const float* __restrict__ Z,
                              float* __restrict__ lossOut) {
    int lane = threadIdx.x & 63;
    int wid = threadIdx.x >> 6;
    int gw = blockIdx.x * 4 + wid;        // 256 waves total
    float acc = 0.f;
    for (int row = gw; row < N_TOT; row += 256) {
        int pos = (row + B_DIM) & (N_TOT - 1);
        float2 a = *(const float2*)(znf + (size_t)row * D_DIM + lane * 2);
        float2 p = *(const float2*)(znf + (size_t)pos * D_DIM + lane * 2);
        float d = waveReduceSum(a.x * p.x + a.y * p.y);
        acc += logf(Z[row]) - d * TEMP_INV;
    }
    __shared__ float part[4];
    if (lane == 0) part[wid] = acc;
    __syncthreads();
    if (threadIdx.x == 0) {
        float t = (part[0] + part[1] + part[2] + part[3]) * (1.0f / N_TOT);
        atomicAdd(lossOut, t);
    }
}

extern "C" void kernel_launch(void* const* d_in, const int* in_sizes, int n_in,
                              void* d_out, int out_size, void* d_ws, size_t ws_size,
                              hipStream_t stream) {
    const float* feat = (const float*)d_in[0];
    float* out = (float*)d_out;

    // Workspace layout: znf (4 MB) | znb (2 MB) | Z (32 KB)
    float* znf = (float*)d_ws;
    ushort* znb = (ushort*)((char*)d_ws + (4u << 20));
    float* Z = (float*)((char*)d_ws + (6u << 20));

    normalize_kernel<<<dim3(2048), dim3(256), 0, stream>>>(feat, znf, znb, Z, out);
    sim_kernel<<<dim3(64, 64), dim3(256), 0, stream>>>(znb, Z);
    reduce_kernel<<<dim3(64), dim3(256), 0, stream>>>(znf, Z, out);
}

// Round 2
// 110.928 us; speedup vs baseline: 1.0317x; 1.0317x over previous
//
#include <hip/hip_runtime.h>
#include <hip/hip_bf16.h>

#define B_DIM 4096
#define V_DIM 2
#define D_DIM 128
#define N_TOT 8192
#define TEMP_INV (1.0f / 0.07f)

typedef float f32x4 __attribute__((ext_vector_type(4)));
typedef __bf16 bf16x8 __attribute__((ext_vector_type(8)));

__device__ __forceinline__ float waveReduceSum(float v) {
#pragma unroll
    for (int off = 32; off > 0; off >>= 1) v += __shfl_xor(v, off);
    return v;
}

// Kernel 1: normalize rows into view-major order (i = v*B + b); emit fp32 + bf16.
// Also zeroes Z and the output accumulator (ws/out are poisoned 0xAA each launch).
__global__ void normalize_kernel(const float* __restrict__ feat,
                                 float* __restrict__ znf,
                                 ushort* __restrict__ znb,
                                 float* __restrict__ Z,
                                 float* __restrict__ lossOut) {
    int gid = blockIdx.x * 256 + threadIdx.x;
    if (gid < N_TOT) Z[gid] = 0.f;
    if (gid == 0) lossOut[0] = 0.f;

    int row = blockIdx.x * 4 + (threadIdx.x >> 6);   // 2048 blocks * 4 waves = 8192 rows
    int lane = threadIdx.x & 63;
    int b = row & (B_DIM - 1);
    int v = row >> 12;                                // B = 4096 = 2^12
    const float* src = feat + ((size_t)b * V_DIM + v) * D_DIM;
    float2 x = *(const float2*)(src + lane * 2);
    float ss = waveReduceSum(x.x * x.x + x.y * x.y);
    float inv = 1.0f / fmaxf(sqrtf(ss), 1e-8f);       // torch CosineSimilarity eps clamp
    float z0 = x.x * inv, z1 = x.y * inv;
    *(float2*)(znf + (size_t)row * D_DIM + lane * 2) = make_float2(z0, z1);
    __hip_bfloat16 h0 = __float2bfloat16(z0);
    __hip_bfloat16 h1 = __float2bfloat16(z1);
    ushort2 u;
    u.x = *reinterpret_cast<ushort*>(&h0);
    u.y = *reinterpret_cast<ushort*>(&h1);
    *(ushort2*)(znb + (size_t)row * D_DIM + lane * 2) = u;
}

// Kernel 2: upper-triangle 128x128 tiles of S = zn.znT / T; fragments loaded
// DIRECTLY from global (znb is 2 MB -> L2-resident; LDS staging was pure
// overhead + bank conflicts + occupancy cap). Off-diagonal tiles accumulate
// exp row-sums for the i-range AND exp col-sums for the j-range (symmetry).
__global__ __launch_bounds__(256) void sim_kernel(const ushort* __restrict__ znb,
                                                  float* __restrict__ Z) {
    __shared__ float rowsum[2][128];
    __shared__ float colsum[2][128];

    // Decode upper-triangle tile index: ti in [0,64), tj in [ti,64).
    // f(t) = t*(129-t)/2 tiles precede row t.
    const int idx = blockIdx.x;
    int ti = (int)((129.0f - sqrtf(16641.0f - 8.0f * (float)idx)) * 0.5f);
    while ((ti + 1) * (129 - (ti + 1)) / 2 <= idx) ++ti;   // fp-safety correction
    while (ti * (129 - ti) / 2 > idx) --ti;
    const int tj = ti + (idx - ti * (129 - ti) / 2);
    const int i0 = ti * 128, j0 = tj * 128;
    const bool isDiag = (ti == tj);

    const int tid = threadIdx.x;
    const int lane = tid & 63;
    const int wid = tid >> 6;
    const int wr = wid >> 1, wc = wid & 1;   // 2x2 wave grid, 64x64 per wave
    const int l16 = lane & 15;
    const int grp = lane >> 4;

    // Per-lane fragment base addresses (row-major, 256 B/row); kk walks via imm offs.
    const char* zb = (const char*)znb;
    const char* aBase[4];
    const char* bBase[4];
#pragma unroll
    for (int m = 0; m < 4; ++m)
        aBase[m] = zb + (size_t)(i0 + wr * 64 + m * 16 + l16) * 256 + grp * 16;
#pragma unroll
    for (int n = 0; n < 4; ++n)
        bBase[n] = zb + (size_t)(j0 + wc * 64 + n * 16 + l16) * 256 + grp * 16;

    f32x4 acc[4][4] = {};
#pragma unroll
    for (int kk = 0; kk < 4; ++kk) {
        bf16x8 af[4], bf[4];
#pragma unroll
        for (int m = 0; m < 4; ++m) af[m] = *(const bf16x8*)(aBase[m] + kk * 64);
#pragma unroll
        for (int n = 0; n < 4; ++n) bf[n] = *(const bf16x8*)(bBase[n] + kk * 64);
#pragma unroll
        for (int m = 0; m < 4; ++m)
#pragma unroll
            for (int n = 0; n < 4; ++n)
                acc[m][n] = __builtin_amdgcn_mfma_f32_16x16x32_bf16(af[m], bf[n], acc[m][n], 0, 0, 0);
    }

    // Epilogue: scale, exp, diagonal mask (diag tiles only), row + col partial sums.
    // C/D layout: col = lane&15, row = (lane>>4)*4 + reg.
    float esumR[4][4];
    float esumC[4];
#pragma unroll
    for (int m = 0; m < 4; ++m)
#pragma unroll
        for (int r = 0; r < 4; ++r) esumR[m][r] = 0.f;
#pragma unroll
    for (int n = 0; n < 4; ++n) esumC[n] = 0.f;

#pragma unroll
    for (int m = 0; m < 4; ++m) {
#pragma unroll
        for (int n = 0; n < 4; ++n) {
#pragma unroll
            for (int r = 0; r < 4; ++r) {
                float e = __expf(acc[m][n][r] * TEMP_INV);
                if (isDiag) {
                    int giL = wr * 64 + m * 16 + grp * 4 + r;
                    int gjL = wc * 64 + n * 16 + l16;
                    if (giL == gjL) e = 0.f;     // exclude self-contrast
                }
                esumR[m][r] += e;
                esumC[n] += e;
            }
        }
    }

    // Row sums: reduce across the 16 cols held by l16 lanes.
#pragma unroll
    for (int m = 0; m < 4; ++m) {
#pragma unroll
        for (int r = 0; r < 4; ++r) {
            float vsum = esumR[m][r];
            vsum += __shfl_xor(vsum, 1);
            vsum += __shfl_xor(vsum, 2);
            vsum += __shfl_xor(vsum, 4);
            vsum += __shfl_xor(vsum, 8);
            if (l16 == 0) rowsum[wc][wr * 64 + m * 16 + grp * 4 + r] = vsum;
        }
    }
    // Col sums: reduce across the 4 row-groups (grp) spread over lanes 16/32 apart.
#pragma unroll
    for (int n = 0; n < 4; ++n) {
        float csum = esumC[n];
        csum += __shfl_xor(csum, 16);
        csum += __shfl_xor(csum, 32);
        if (grp == 0) colsum[wr][wc * 64 + n * 16 + l16] = csum;
    }
    __syncthreads();

    if (tid < 128) {
        atomicAdd(&Z[i0 + tid], rowsum[0][tid] + rowsum[1][tid]);
    } else if (!isDiag) {
        int c = tid - 128;
        atomicAdd(&Z[j0 + c], colsum[0][c] + colsum[1][c]);
    }
}

// Kernel 3: loss = mean_i( log(Z_i) - dot(zn_i, zn_pos(i))/T ), pos(i) = (i+B) mod N.
__global__ void reduce_kernel(const float* __restrict__ znf,
                              const float* __restrict__ Z,
                              float* __restrict__ lossOut) {
    int lane = threadIdx.x & 63;
    int wid = threadIdx.x >> 6;
    float acc = 0.f;
    int base = blockIdx.x * 16 + wid * 4;   // 512 blocks * 4 waves * 4 rows
#pragma unroll
    for (int k = 0; k < 4; ++k) {
        int row = base + k;
        int pos = (row + B_DIM) & (N_TOT - 1);
        float2 a = *(const float2*)(znf + (size_t)row * D_DIM + lane * 2);
        float2 p = *(const float2*)(znf + (size_t)pos * D_DIM + lane * 2);
        float d = waveReduceSum(a.x * p.x + a.y * p.y);
        acc += logf(Z[row]) - d * TEMP_INV;
    }
    __shared__ float part[4];
    if (lane == 0) part[wid] = acc;
    __syncthreads();
    if (threadIdx.x == 0) {
        float t = (part[0] + part[1] + part[2] + part[3]) * (1.0f / N_TOT);
        atomicAdd(lossOut, t);
    }
}

extern "C" void kernel_launch(void* const* d_in, const int* in_sizes, int n_in,
                              void* d_out, int out_size, void* d_ws, size_t ws_size,
                              hipStream_t stream) {
    const float* feat = (const float*)d_in[0];
    float* out = (float*)d_out;

    // Workspace layout: znf (4 MB) | znb (2 MB) | Z (32 KB)
    float* znf = (float*)d_ws;
    ushort* znb = (ushort*)((char*)d_ws + (4u << 20));
    float* Z = (float*)((char*)d_ws + (6u << 20));

    normalize_kernel<<<dim3(2048), dim3(256), 0, stream>>>(feat, znf, znb, Z, out);
    sim_kernel<<<dim3(2080), dim3(256), 0, stream>>>(znb, Z);
    reduce_kernel<<<dim3(512), dim3(256), 0, stream>>>(znf, Z, out);
}

// Round 3
// 90.356 us; speedup vs baseline: 1.2666x; 1.2277x over previous
//
#include <hip/hip_runtime.h>
#include <hip/hip_bf16.h>

#define B_DIM 4096
#define N_TOT 8192
#define TEMP_INV (1.0f / 0.07f)
// exp(x*TEMP_INV) == exp2(x * TEMP_INV*log2(e))
#define EXP2S (TEMP_INV * 1.4426950408889634f)

typedef float f32x4 __attribute__((ext_vector_type(4)));
typedef __bf16 bf16x8 __attribute__((ext_vector_type(8)));

__device__ __forceinline__ float waveReduceSum(float v) {
#pragma unroll
    for (int off = 32; off > 0; off >>= 1) v += __shfl_xor(v, off);
    return v;
}

// async 16B global->LDS DMA: LDS dest = wave-uniform base + lane*16 (linear).
#define GLOAD16(gsrc, ldst)                                                      \
    __builtin_amdgcn_global_load_lds(                                            \
        (const __attribute__((address_space(1))) void*)(gsrc),                   \
        (__attribute__((address_space(3))) void*)(ldst), 16, 0, 0)

// Kernel 1: normalize rows into view-major order (i = v*B + b); emit bf16 only.
// Zeroes Z / posAcc / lossOut (ws and out are re-poisoned before every launch).
__global__ void normalize_kernel(const float* __restrict__ feat,
                                 ushort* __restrict__ znb,
                                 float* __restrict__ Z,
                                 float* __restrict__ posAcc,
                                 float* __restrict__ lossOut) {
    int gid = blockIdx.x * 256 + threadIdx.x;
    if (gid < N_TOT) Z[gid] = 0.f;
    if (gid == 0) { lossOut[0] = 0.f; posAcc[0] = 0.f; }

    int row = blockIdx.x * 4 + (threadIdx.x >> 6);   // 2048 blocks * 4 waves
    int lane = threadIdx.x & 63;
    int b = row & (B_DIM - 1);
    int v = row >> 12;
    const float* src = feat + ((size_t)b * 2 + v) * 128;
    float2 x = *(const float2*)(src + lane * 2);
    float ss = waveReduceSum(x.x * x.x + x.y * x.y);
    float inv = 1.0f / fmaxf(sqrtf(ss), 1e-8f);
    __hip_bfloat16 h0 = __float2bfloat16(x.x * inv);
    __hip_bfloat16 h1 = __float2bfloat16(x.y * inv);
    ushort2 u;
    u.x = *reinterpret_cast<ushort*>(&h0);
    u.y = *reinterpret_cast<ushort*>(&h1);
    *(ushort2*)(znb + (size_t)row * 128 + lane * 2) = u;
}

// Kernel 2: upper-triangle 128x128 tiles of S = zn.znT; fused exp2 + row/col sums.
// K=128 fully staged via global_load_lds (async DMA, linear LDS dest) with the
// XOR swizzle applied on the GLOBAL source side (rule: both-sides-or-neither),
// read back with the same swizzle. Diagonal self-terms and positive-pair dots
// handled post-hoc on the 64 / 32 special tiles only.
__global__ __launch_bounds__(256, 2) void sim_kernel(const ushort* __restrict__ znb,
                                                     float* __restrict__ Z,
                                                     float* __restrict__ posAcc) {
    __shared__ __align__(16) ushort As[128 * 128];
    __shared__ __align__(16) ushort Bs[128 * 128];
    __shared__ float rowsum[2][128];
    __shared__ float colsum[2][128];

    // Decode upper-triangle tile index: ti in [0,64), tj in [ti,64).
    const int idx = blockIdx.x;
    int ti = (int)((129.0f - sqrtf(16641.0f - 8.0f * (float)idx)) * 0.5f);
    while ((ti + 1) * (129 - (ti + 1)) / 2 <= idx) ++ti;
    while (ti * (129 - ti) / 2 > idx) --ti;
    const int tj = ti + (idx - ti * (129 - ti) / 2);
    const int i0 = ti * 128, j0 = tj * 128;
    const bool isDiag = (ti == tj);
    const bool isPos = (tj == ti + 32);   // local diag = S[i, i+B]

    const int tid = threadIdx.x;
    const int lane = tid & 63;
    const int wid = tid >> 6;
    const int wr = wid >> 1, wc = wid & 1;   // 2x2 wave grid, 64x64 per wave
    const int l16 = lane & 15;
    const int grp = lane >> 4;

    // ---- Stage A & B tiles: 8 iters x (2 DMA per wave). Source chunk index is
    // pre-swizzled so the linear DMA write leaves LDS[row][ch] = g[row][ch^(row&7)].
    {
        const ushort* gA = znb + (size_t)i0 * 128;
        const ushort* gB = znb + (size_t)j0 * 128;
        int cb = wid * 64;                    // wave-uniform chunk base
        int c = cb + lane;
#pragma unroll
        for (int it = 0; it < 8; ++it) {
            int row = c >> 4, ch = c & 15;
            int sch = ch ^ (row & 7);
            GLOAD16(gA + row * 128 + sch * 8, As + cb * 8);
            GLOAD16(gB + row * 128 + sch * 8, Bs + cb * 8);
            cb += 256;
            c += 256;
        }
    }
    __syncthreads();   // drains vmcnt(0): all DMA landed

    // ---- MFMA: 4x4 fragments of 16x16x32, K = 4 x 32.
    const int r7s = (l16 & 7) << 4;          // read-side swizzle bits
    f32x4 acc[4][4] = {};
#pragma unroll
    for (int kk = 0; kk < 4; ++kk) {
        const int kb = kk * 64 + grp * 16;
        bf16x8 af[4], bf[4];
#pragma unroll
        for (int m = 0; m < 4; ++m) {
            int r = wr * 64 + m * 16 + l16;
            af[m] = *(const bf16x8*)((const char*)As + r * 256 + (kb ^ r7s));
        }
#pragma unroll
        for (int n = 0; n < 4; ++n) {
            int r = wc * 64 + n * 16 + l16;
            bf[n] = *(const bf16x8*)((const char*)Bs + r * 256 + (kb ^ r7s));
        }
#pragma unroll
        for (int m = 0; m < 4; ++m)
#pragma unroll
            for (int n = 0; n < 4; ++n)
                acc[m][n] = __builtin_amdgcn_mfma_f32_16x16x32_bf16(af[m], bf[n], acc[m][n], 0, 0, 0);
    }

    // ---- Epilogue. C/D layout: col = lane&15, row = (lane>>4)*4 + reg.
    float esumR[4][4];
    float esumC[4] = {0.f, 0.f, 0.f, 0.f};
#pragma unroll
    for (int m = 0; m < 4; ++m)
#pragma unroll
        for (int r = 0; r < 4; ++r) esumR[m][r] = 0.f;

#pragma unroll
    for (int m = 0; m < 4; ++m)
#pragma unroll
        for (int n = 0; n < 4; ++n)
#pragma unroll
            for (int r = 0; r < 4; ++r) {
                float e = exp2f(acc[m][n][r] * EXP2S);
                esumR[m][r] += e;
                esumC[n] += e;
            }

    // Self-contrast removal (diag tiles only): lane holds local (x,x) iff
    // wr==wc and l16 == grp*4 + r; subtract its exp contribution post-hoc.
    const int rsel = l16 - grp * 4;
    const bool selfLane = (wr == wc) && (rsel >= 0 && rsel < 4);
    if (isDiag && selfLane) {
#pragma unroll
        for (int m = 0; m < 4; ++m) {
            float e = exp2f(acc[m][m][rsel] * EXP2S);
            esumR[m][rsel] -= e;
            esumC[m] -= e;
        }
    }
    // Positive-pair dots: tiles tj==ti+32, local diag = S[i, i+B] (raw cosine).
    if (isPos) {
        float pd = 0.f;
        if (selfLane) {
#pragma unroll
            for (int m = 0; m < 4; ++m) pd += acc[m][m][rsel];
        }
        pd = waveReduceSum(pd);
        if (lane == 0 && wr == wc) atomicAdd(posAcc, pd);
    }

    // Row sums: reduce across 16 cols held by the l16 group.
#pragma unroll
    for (int m = 0; m < 4; ++m)
#pragma unroll
        for (int r = 0; r < 4; ++r) {
            float vsum = esumR[m][r];
            vsum += __shfl_xor(vsum, 1);
            vsum += __shfl_xor(vsum, 2);
            vsum += __shfl_xor(vsum, 4);
            vsum += __shfl_xor(vsum, 8);
            if (l16 == 0) rowsum[wc][wr * 64 + m * 16 + grp * 4 + r] = vsum;
        }
    // Col sums: reduce across the 4 row-groups (lanes 16/32 apart).
#pragma unroll
    for (int n = 0; n < 4; ++n) {
        float csum = esumC[n];
        csum += __shfl_xor(csum, 16);
        csum += __shfl_xor(csum, 32);
        if (grp == 0) colsum[wr][wc * 64 + n * 16 + l16] = csum;
    }
    __syncthreads();

    if (tid < 128) {
        atomicAdd(&Z[i0 + tid], rowsum[0][tid] + rowsum[1][tid]);
    } else if (!isDiag) {
        int c = tid - 128;
        atomicAdd(&Z[j0 + c], colsum[0][c] + colsum[1][c]);
    }
}

// Kernel 3: loss = (1/N) * ( sum_i log Z_i - TEMP_INV * 2 * posAcc ).
__global__ void finalize_kernel(const float* __restrict__ Z,
                                const float* __restrict__ posAcc,
                                float* __restrict__ lossOut) {
    int row = blockIdx.x * 256 + threadIdx.x;
    float v = logf(Z[row]);
    v = waveReduceSum(v);
    __shared__ float part[4];
    int lane = threadIdx.x & 63, wid = threadIdx.x >> 6;
    if (lane == 0) part[wid] = v;
    __syncthreads();
    if (threadIdx.x == 0) {
        float s = part[0] + part[1] + part[2] + part[3];
        if (blockIdx.x == 0) s -= 2.0f * TEMP_INV * posAcc[0];
        atomicAdd(lossOut, s * (1.0f / N_TOT));
    }
}

extern "C" void kernel_launch(void* const* d_in, const int* in_sizes, int n_in,
                              void* d_out, int out_size, void* d_ws, size_t ws_size,
                              hipStream_t stream) {
    const float* feat = (const float*)d_in[0];
    float* out = (float*)d_out;

    // ws layout: znb (2 MB) | Z (32 KB) | posAcc (4 B)
    ushort* znb = (ushort*)d_ws;
    float* Z = (float*)((char*)d_ws + (2u << 20));
    float* posAcc = (float*)((char*)d_ws + (2u << 20) + 32768);

    normalize_kernel<<<dim3(2048), dim3(256), 0, stream>>>(feat, znb, Z, posAcc, out);
    sim_kernel<<<dim3(2080), dim3(256), 0, stream>>>(znb, Z, posAcc);
    finalize_kernel<<<dim3(32), dim3(256), 0, stream>>>(Z, posAcc, out);
}